// Round 2
// baseline (359.691 us; speedup 1.0000x reference)
//
#include <hip/hip_runtime.h>
#include <type_traits>
#include <utility>

// ---------------- problem constants ----------------
#define B_    8
#define NQ_   1024
#define I_    21760      // 128*128 + 64*64 + 32*32 + 16*16
#define EMB_  256
#define HID_  256
#define H_    8
#define CH_   32

typedef float  f32x4  __attribute__((ext_vector_type(4)));
typedef __bf16 bf16x8 __attribute__((ext_vector_type(8)));
typedef short  s16x8  __attribute__((ext_vector_type(8)));

// ---- MFMA shim: works whether the builtin wants v8bf16 or v8i16 ----
template <typename V, typename = void>
struct bf16_mfma_native : std::false_type {};
template <typename V>
struct bf16_mfma_native<V, std::void_t<decltype(__builtin_amdgcn_mfma_f32_16x16x32_bf16(
    std::declval<V>(), std::declval<V>(), std::declval<f32x4>(), 0, 0, 0))>>
    : std::true_type {};

template <typename V>
__device__ __forceinline__ f32x4 mfma_dispatch(V a, V b, f32x4 c) {
  if constexpr (bf16_mfma_native<V>::value) {
    return __builtin_amdgcn_mfma_f32_16x16x32_bf16(a, b, c, 0, 0, 0);
  } else {
    return __builtin_amdgcn_mfma_f32_16x16x32_bf16(
        __builtin_bit_cast(s16x8, a), __builtin_bit_cast(s16x8, b), c, 0, 0, 0);
  }
}

__device__ __forceinline__ f32x4 MFMA(s16x8 a, s16x8 b, f32x4 c) {
  return mfma_dispatch(__builtin_bit_cast(bf16x8, a), __builtin_bit_cast(bf16x8, b), c);
}

// float -> bf16 bits, round-to-nearest-even
__device__ __forceinline__ unsigned short f2bf(float f) {
  unsigned u = __float_as_uint(f);
  u += 0x7fffu + ((u >> 16) & 1u);
  return (unsigned short)(u >> 16);
}

// ---------------------------------------------------------------
// Generic GEMM, K fixed = 256:  Out[M,N] = A[M,256] @ W[256,N] + bias
// 512 threads = 8 waves. Wave w owns columns {s*128 + w*16 .. +15}.
// W strip held in registers. A tile (32x256) staged fp32->bf16 in LDS.
// ---------------------------------------------------------------
template <int NS, bool OUT_BF16>
__global__ __launch_bounds__(512) void gemm_k256(
    const float* __restrict__ A, const float* __restrict__ W,
    const float* __restrict__ bias, void* __restrict__ Out,
    const int N, const int Mtiles) {
  __shared__ __align__(16) short lds[32 * 264];
  const int tid  = threadIdx.x;
  const int lane = tid & 63;
  const int wave = tid >> 6;
  const int quad = lane >> 4;
  const int ln   = lane & 15;

  // --- load W fragments (one-time; L2-resident) ---
  s16x8 bfrag[NS][8];
  float bv[NS];
#pragma unroll
  for (int st = 0; st < NS; ++st) {
    const int ng = st * 128 + wave * 16 + ln;
    bv[st] = bias[ng];
#pragma unroll
    for (int ks = 0; ks < 8; ++ks) {
      s16x8 f;
#pragma unroll
      for (int j = 0; j < 8; ++j)
        f[j] = (short)f2bf(W[(ks * 32 + quad * 8 + j) * N + ng]);
      bfrag[st][ks] = f;
    }
  }

  const int sr = tid >> 4;          // staging row 0..31
  const int sc = (tid & 15) * 16;   // staging col (16 floats per thread)

  for (int t = blockIdx.x; t < Mtiles; t += gridDim.x) {
    const size_t rowBase = (size_t)t * 32;
    {
      const float4* src = (const float4*)(A + (rowBase + sr) * 256 + sc);
      float4 v0 = src[0], v1 = src[1], v2 = src[2], v3 = src[3];
      s16x8 p0, p1;
      p0[0] = (short)f2bf(v0.x); p0[1] = (short)f2bf(v0.y);
      p0[2] = (short)f2bf(v0.z); p0[3] = (short)f2bf(v0.w);
      p0[4] = (short)f2bf(v1.x); p0[5] = (short)f2bf(v1.y);
      p0[6] = (short)f2bf(v1.z); p0[7] = (short)f2bf(v1.w);
      p1[0] = (short)f2bf(v2.x); p1[1] = (short)f2bf(v2.y);
      p1[2] = (short)f2bf(v2.z); p1[3] = (short)f2bf(v2.w);
      p1[4] = (short)f2bf(v3.x); p1[5] = (short)f2bf(v3.y);
      p1[6] = (short)f2bf(v3.z); p1[7] = (short)f2bf(v3.w);
      *(s16x8*)&lds[sr * 264 + sc]     = p0;
      *(s16x8*)&lds[sr * 264 + sc + 8] = p1;
    }
    __syncthreads();

    f32x4 acc[NS][2];
#pragma unroll
    for (int st = 0; st < NS; ++st) {
      acc[st][0] = f32x4{bv[st], bv[st], bv[st], bv[st]};
      acc[st][1] = acc[st][0];
    }
#pragma unroll
    for (int ks = 0; ks < 8; ++ks) {
      s16x8 a0 = *(const s16x8*)&lds[ln * 264 + ks * 32 + quad * 8];
      s16x8 a1 = *(const s16x8*)&lds[(ln + 16) * 264 + ks * 32 + quad * 8];
#pragma unroll
      for (int st = 0; st < NS; ++st) {
        acc[st][0] = MFMA(a0, bfrag[st][ks], acc[st][0]);
        acc[st][1] = MFMA(a1, bfrag[st][ks], acc[st][1]);
      }
    }
#pragma unroll
    for (int st = 0; st < NS; ++st) {
      const int ng = st * 128 + wave * 16 + ln;
#pragma unroll
      for (int rt = 0; rt < 2; ++rt) {
#pragma unroll
        for (int r = 0; r < 4; ++r) {
          const size_t m = rowBase + rt * 16 + quad * 4 + r;
          if constexpr (OUT_BF16)
            ((unsigned short*)Out)[m * N + ng] = f2bf(acc[st][rt][r]);
          else
            ((float*)Out)[m * N + ng] = acc[st][rt][r];
        }
      }
    }
    __syncthreads();
  }
}

// ---------------------------------------------------------------
// Fused: qp = queries@W_q + b_q  (N=384), then per-(q,h) softmax over
// 16 logits + sampling-point computation — all in one block per
// 32-query tile. Epilogue goes through LDS (aliased with A staging).
// ---------------------------------------------------------------
__global__ __launch_bounds__(512) void qproj_softmax_kernel(
    const float* __restrict__ A, const float* __restrict__ W,
    const float* __restrict__ bias, const float* __restrict__ refp,
    float* __restrict__ attn, float* __restrict__ pts) {
  constexpr int N = 384;
  __shared__ __align__(16) char smem[32 * 392 * 4];  // max(staging 16.9KB, out 50.2KB)
  short* slds = (short*)smem;
  float* sout = (float*)smem;
  const int tid  = threadIdx.x;
  const int lane = tid & 63;
  const int wave = tid >> 6;
  const int quad = lane >> 4;
  const int ln   = lane & 15;

  s16x8 bfrag[3][8];
  float bv[3];
#pragma unroll
  for (int st = 0; st < 3; ++st) {
    const int ng = st * 128 + wave * 16 + ln;
    bv[st] = bias[ng];
#pragma unroll
    for (int ks = 0; ks < 8; ++ks) {
      s16x8 f;
#pragma unroll
      for (int j = 0; j < 8; ++j)
        f[j] = (short)f2bf(W[(ks * 32 + quad * 8 + j) * N + ng]);
      bfrag[st][ks] = f;
    }
  }

  const int sr = tid >> 4;
  const int sc = (tid & 15) * 16;
  const size_t rowBase = (size_t)blockIdx.x * 32;
  {
    const float4* src = (const float4*)(A + (rowBase + sr) * 256 + sc);
    float4 v0 = src[0], v1 = src[1], v2 = src[2], v3 = src[3];
    s16x8 p0, p1;
    p0[0] = (short)f2bf(v0.x); p0[1] = (short)f2bf(v0.y);
    p0[2] = (short)f2bf(v0.z); p0[3] = (short)f2bf(v0.w);
    p0[4] = (short)f2bf(v1.x); p0[5] = (short)f2bf(v1.y);
    p0[6] = (short)f2bf(v1.z); p0[7] = (short)f2bf(v1.w);
    p1[0] = (short)f2bf(v2.x); p1[1] = (short)f2bf(v2.y);
    p1[2] = (short)f2bf(v2.z); p1[3] = (short)f2bf(v2.w);
    p1[4] = (short)f2bf(v3.x); p1[5] = (short)f2bf(v3.y);
    p1[6] = (short)f2bf(v3.z); p1[7] = (short)f2bf(v3.w);
    *(s16x8*)&slds[sr * 264 + sc]     = p0;
    *(s16x8*)&slds[sr * 264 + sc + 8] = p1;
  }
  __syncthreads();

  f32x4 acc[3][2];
#pragma unroll
  for (int st = 0; st < 3; ++st) {
    acc[st][0] = f32x4{bv[st], bv[st], bv[st], bv[st]};
    acc[st][1] = acc[st][0];
  }
#pragma unroll
  for (int ks = 0; ks < 8; ++ks) {
    s16x8 a0 = *(const s16x8*)&slds[ln * 264 + ks * 32 + quad * 8];
    s16x8 a1 = *(const s16x8*)&slds[(ln + 16) * 264 + ks * 32 + quad * 8];
#pragma unroll
    for (int st = 0; st < 3; ++st) {
      acc[st][0] = MFMA(a0, bfrag[st][ks], acc[st][0]);
      acc[st][1] = MFMA(a1, bfrag[st][ks], acc[st][1]);
    }
  }
  __syncthreads();  // everyone done reading slds (aliased with sout)

#pragma unroll
  for (int st = 0; st < 3; ++st) {
    const int ng = st * 128 + wave * 16 + ln;
#pragma unroll
    for (int rt = 0; rt < 2; ++rt)
#pragma unroll
      for (int r = 0; r < 4; ++r)
        sout[(rt * 16 + quad * 4 + r) * 392 + ng] = acc[st][rt][r];
  }
  __syncthreads();

  if (tid < 256) {
    const int ql = tid >> 3, h = tid & 7;
    const float* basep = sout + ql * 392 + h * 48;
    float s[16];
    float mx = -1e30f;
#pragma unroll
    for (int lp = 0; lp < 16; ++lp) {
      s[lp] = basep[lp * 3 + 2];
      mx = fmaxf(mx, s[lp]);
    }
    float sum = 0.f;
#pragma unroll
    for (int lp = 0; lp < 16; ++lp) {
      s[lp] = __expf(s[lp] - mx);
      sum += s[lp];
    }
    const float inv = 1.0f / sum;
    const size_t q   = rowBase + ql;
    const size_t gq8 = q * 8 + h;
    float* ao = attn + gq8 * 16;
#pragma unroll
    for (int lp = 0; lp < 16; ++lp) ao[lp] = s[lp] * inv;

    const float rx = refp[q * 2], ry = refp[q * 2 + 1];
    float* po = pts + gq8 * 32;
    const float invsh[4] = {1.f / 128.f, 1.f / 64.f, 1.f / 32.f, 1.f / 16.f};
#pragma unroll
    for (int l = 0; l < 4; ++l) {
#pragma unroll
      for (int p = 0; p < 4; ++p) {
        const int lp = l * 4 + p;
        po[lp * 2 + 0] = rx + basep[lp * 3 + 0] * invsh[l];
        po[lp * 2 + 1] = ry + basep[lp * 3 + 1] * invsh[l];
      }
    }
  }
}

// ---------------------------------------------------------------
// MSDA bilinear sampling + attention-weighted sum.
// 1 block (256 thr) per 4 queries. Phase1: 512 (q,h,lp) items ->
// folded weights + gather bases in LDS. Phase2: 8 threads per
// corner-row, dwordx2 loads (8x64B segments per wave-load).
// ---------------------------------------------------------------
__global__ __launch_bounds__(256) void msda_sample_kernel(
    const unsigned int* __restrict__ imgp,  // bf16 pairs, [B*I][128] uints
    const float* __restrict__ attn, const float* __restrict__ pts,
    float* __restrict__ out) {
  __shared__ __align__(16) float sw[512][4];
  __shared__ __align__(16) int   sib[512][4];
  const int bid = blockIdx.x;        // group of 4 queries
  const int tid = threadIdx.x;

#pragma unroll
  for (int it = 0; it < 2; ++it) {
    const int i  = it * 256 + tid;   // 0..511
    const int q  = i >> 7;
    const int h  = (i >> 4) & 7;
    const int lp = i & 15;
    const int l  = lp >> 2;
    const int gq = bid * 4 + q;
    const int b  = gq >> 10;
    const int ww = 128 >> l;
    const int start = (l > 0 ? 16384 : 0) + (l > 1 ? 4096 : 0) + (l > 2 ? 1024 : 0);
    const float2 p = *(const float2*)&pts[((size_t)gq * 8 + h) * 32 + lp * 2];
    const float a  = attn[((size_t)gq * 8 + h) * 16 + lp];
    const float x = p.x * (float)ww - 0.5f;
    const float y = p.y * (float)ww - 0.5f;
    const float x0f = floorf(x), y0f = floorf(y);
    const float wx = x - x0f, wy = y - y0f;
    const int x0 = (int)x0f, y0 = (int)y0f;
    const float cw[4] = {(1.f - wx) * (1.f - wy), wx * (1.f - wy),
                         (1.f - wx) * wy,          wx * wy};
#pragma unroll
    for (int c = 0; c < 4; ++c) {
      const int xi = x0 + (c & 1), yi = y0 + (c >> 1);
      const bool valid = (xi >= 0) & (xi < ww) & (yi >= 0) & (yi < ww);
      const int xc = min(max(xi, 0), ww - 1);
      const int yc = min(max(yi, 0), ww - 1);
      const int idx = start + yc * ww + xc;
      sw[i][c]  = valid ? a * cw[c] : 0.f;
      sib[i][c] = ((b * I_ + idx) << 7) + (h << 4);  // uint (bf16-pair) units
    }
  }
  __syncthreads();

  const int q  = tid >> 6;        // 0..3
  const int h  = (tid >> 3) & 7;  // 0..7
  const int c4 = tid & 7;         // 0..7, handles channels 4*c4..4*c4+3
  float a0 = 0.f, a1 = 0.f, a2 = 0.f, a3 = 0.f;
#pragma unroll
  for (int lp = 0; lp < 16; ++lp) {
    const int sidx = q * 128 + h * 16 + lp;
    const float4 w4 = *(const float4*)sw[sidx];
    const int4   i4 = *(const int4*)sib[sidx];
    uint2 u;
#define CORNER(IDX, WGT)                                  \
    u = *(const uint2*)&imgp[(IDX) + c4 * 2];             \
    a0 += (WGT) * __uint_as_float(u.x << 16);             \
    a1 += (WGT) * __uint_as_float(u.x & 0xffff0000u);     \
    a2 += (WGT) * __uint_as_float(u.y << 16);             \
    a3 += (WGT) * __uint_as_float(u.y & 0xffff0000u);
    CORNER(i4.x, w4.x)
    CORNER(i4.y, w4.y)
    CORNER(i4.z, w4.z)
    CORNER(i4.w, w4.w)
#undef CORNER
  }
  const int gq = bid * 4 + q;
  float4 r{a0, a1, a2, a3};
  *(float4*)&out[(size_t)gq * 256 + h * 32 + c4 * 4] = r;
}

// ---------------------------------------------------------------
// workspace layout (bytes)
// ---------------------------------------------------------------
#define OFF_IMGP 0ULL                        // 174080*256*2 = 89,128,960 (bf16)
#define OFF_ATTN 89128960ULL                 // 8192*8*16*4  =  4,194,304
#define OFF_PTS  93323264ULL                 // 8192*8*32*4  =  8,388,608
#define OFF_MSDA 101711872ULL                // 8192*256*4   =  8,388,608
#define WS_NEEDED 110100480ULL

extern "C" void kernel_launch(void* const* d_in, const int* in_sizes, int n_in,
                              void* d_out, int out_size, void* d_ws, size_t ws_size,
                              hipStream_t stream) {
  const float* img     = (const float*)d_in[0];
  const float* queries = (const float*)d_in[2];
  const float* refp    = (const float*)d_in[3];
  const float* W_img   = (const float*)d_in[4];
  const float* b_img   = (const float*)d_in[5];
  const float* W_q     = (const float*)d_in[6];
  const float* b_q     = (const float*)d_in[7];
  const float* W_out   = (const float*)d_in[8];
  const float* b_out   = (const float*)d_in[9];

  if (ws_size < WS_NEEDED) return;

  char* ws = (char*)d_ws;
  unsigned short* imgp = (unsigned short*)(ws + OFF_IMGP);
  float* attn = (float*)(ws + OFF_ATTN);
  float* pts  = (float*)(ws + OFF_PTS);
  float* msda = (float*)(ws + OFF_MSDA);

  // img_p = img @ W_img + b_img   (174080 x 256) -> bf16; 5440 tiles / 544 blocks = 10 each
  hipLaunchKernelGGL((gemm_k256<2, true>), dim3(544), dim3(512), 0, stream,
                     img, W_img, b_img, (void*)imgp, 256, I_ * B_ / 32);
  // fused qp GEMM + softmax + sampling points
  hipLaunchKernelGGL(qproj_softmax_kernel, dim3(B_ * NQ_ / 32), dim3(512), 0, stream,
                     queries, W_q, b_q, refp, attn, pts);
  // bilinear sampling + attention reduce (4 queries per block)
  hipLaunchKernelGGL(msda_sample_kernel, dim3(B_ * NQ_ / 4), dim3(256), 0, stream,
                     (const unsigned int*)imgp, attn, pts, msda);
  // out = msda @ W_out + b_out    (8192 x 256) -> fp32
  hipLaunchKernelGGL((gemm_k256<2, false>), dim3(256), dim3(512), 0, stream,
                     msda, W_out, b_out, d_out, 256, B_ * NQ_ / 32);
}

// Round 3
// 340.579 us; speedup vs baseline: 1.0561x; 1.0561x over previous
//
#include <hip/hip_runtime.h>
#include <type_traits>
#include <utility>

// ---------------- problem constants ----------------
#define B_    8
#define NQ_   1024
#define I_    21760      // 128*128 + 64*64 + 32*32 + 16*16
#define EMB_  256
#define HID_  256
#define H_    8
#define CH_   32

typedef float  f32x4  __attribute__((ext_vector_type(4)));
typedef __bf16 bf16x8 __attribute__((ext_vector_type(8)));
typedef short  s16x8  __attribute__((ext_vector_type(8)));

// ---- MFMA shim: works whether the builtin wants v8bf16 or v8i16 ----
template <typename V, typename = void>
struct bf16_mfma_native : std::false_type {};
template <typename V>
struct bf16_mfma_native<V, std::void_t<decltype(__builtin_amdgcn_mfma_f32_16x16x32_bf16(
    std::declval<V>(), std::declval<V>(), std::declval<f32x4>(), 0, 0, 0))>>
    : std::true_type {};

template <typename V>
__device__ __forceinline__ f32x4 mfma_dispatch(V a, V b, f32x4 c) {
  if constexpr (bf16_mfma_native<V>::value) {
    return __builtin_amdgcn_mfma_f32_16x16x32_bf16(a, b, c, 0, 0, 0);
  } else {
    return __builtin_amdgcn_mfma_f32_16x16x32_bf16(
        __builtin_bit_cast(s16x8, a), __builtin_bit_cast(s16x8, b), c, 0, 0, 0);
  }
}

__device__ __forceinline__ f32x4 MFMA(s16x8 a, s16x8 b, f32x4 c) {
  return mfma_dispatch(__builtin_bit_cast(bf16x8, a), __builtin_bit_cast(bf16x8, b), c);
}

// float -> bf16 bits, round-to-nearest-even
__device__ __forceinline__ unsigned short f2bf(float f) {
  unsigned u = __float_as_uint(f);
  u += 0x7fffu + ((u >> 16) & 1u);
  return (unsigned short)(u >> 16);
}

// ---------------------------------------------------------------
// GEMM v2, K=256, N=256: Out[M,256] = A[M,256] @ W[256,256] + bias
// 512 thr / 8 waves, M-tile = 64, double-buffered LDS, register
// prefetch of tile t+stride during compute of tile t.
// Wave w owns cols {st*128 + w*16 .. +15}, st in {0,1}; W strip in
// VGPRs (64). MFMA operands SWAPPED (W as A-op) so each thread's
// 4 acc regs are 4 consecutive output columns -> packed stores.
// __launch_bounds__(512,2): VGPR cap 256, 1 block/CU.
// ---------------------------------------------------------------
template <bool OUT_BF16>
__global__ __launch_bounds__(512, 2) void gemm64(
    const float* __restrict__ A, const float* __restrict__ W,
    const float* __restrict__ bias, void* __restrict__ Out,
    const int Mtiles) {
  constexpr int N = 256;
  constexpr int LDSTRIDE = 272;  // shorts; 544 B rows, 16B-aligned frags
  __shared__ __align__(16) short lds[2][64 * LDSTRIDE];
  const int tid  = threadIdx.x;
  const int lane = tid & 63;
  const int wave = tid >> 6;
  const int quad = lane >> 4;
  const int ln   = lane & 15;

  // --- one-time W fragment + bias load (L2-resident) ---
  s16x8 bfrag[2][8];
  f32x4 bias4[2];
#pragma unroll
  for (int st = 0; st < 2; ++st) {
    const int ng = st * 128 + wave * 16 + ln;
    bias4[st] = *(const f32x4*)&bias[st * 128 + wave * 16 + quad * 4];
#pragma unroll
    for (int ks = 0; ks < 8; ++ks) {
      s16x8 f;
#pragma unroll
      for (int j = 0; j < 8; ++j)
        f[j] = (short)f2bf(W[(ks * 32 + quad * 8 + j) * N + ng]);
      bfrag[st][ks] = f;
    }
  }

  // staging map: f4-index i = j*512 + tid -> row = i>>6 (const per wave
  // instr), col4 = lane. Loads are contiguous 1KB per wave-instruction.
  const int srow0 = wave * 8;  // + j at iteration j... actually row = j*8 + wave

  float4 pf[8];
  int t = blockIdx.x;
  {
    const float* Ab = A + (size_t)t * 64 * 256;
#pragma unroll
    for (int j = 0; j < 8; ++j) pf[j] = ((const float4*)Ab)[j * 512 + tid];
#pragma unroll
    for (int j = 0; j < 8; ++j) {
      const int row = j * 8 + wave;
      uint2 u;
      u.x = (unsigned)f2bf(pf[j].x) | ((unsigned)f2bf(pf[j].y) << 16);
      u.y = (unsigned)f2bf(pf[j].z) | ((unsigned)f2bf(pf[j].w) << 16);
      *(uint2*)&lds[0][row * LDSTRIDE + lane * 4] = u;
    }
  }
  __syncthreads();
  (void)srow0;

  int p = 0;
  while (t < Mtiles) {
    const int tn = t + gridDim.x;
    const bool more = (tn < Mtiles);
    if (more) {
      const float* Ab = A + (size_t)tn * 64 * 256;
#pragma unroll
      for (int j = 0; j < 8; ++j) pf[j] = ((const float4*)Ab)[j * 512 + tid];
    }

    // ---- compute tile t from lds[p] ----
    f32x4 acc[2][4];
#pragma unroll
    for (int st = 0; st < 2; ++st)
#pragma unroll
      for (int rt = 0; rt < 4; ++rt) acc[st][rt] = bias4[st];

#pragma unroll
    for (int ks = 0; ks < 8; ++ks) {
      s16x8 a[4];
#pragma unroll
      for (int rt = 0; rt < 4; ++rt)
        a[rt] = *(const s16x8*)&lds[p][(rt * 16 + ln) * LDSTRIDE + ks * 32 + quad * 8];
#pragma unroll
      for (int st = 0; st < 2; ++st)
#pragma unroll
        for (int rt = 0; rt < 4; ++rt)
          acc[st][rt] = MFMA(bfrag[st][ks], a[rt], acc[st][rt]);
    }

    // ---- epilogue: thread holds cols {col..col+3} of row (rowBase+rt*16+ln)
    const size_t rowBase = (size_t)t * 64;
#pragma unroll
    for (int st = 0; st < 2; ++st) {
      const int col = st * 128 + wave * 16 + quad * 4;
#pragma unroll
      for (int rt = 0; rt < 4; ++rt) {
        const size_t row = rowBase + rt * 16 + ln;
        if constexpr (OUT_BF16) {
          uint2 u;
          u.x = (unsigned)f2bf(acc[st][rt][0]) | ((unsigned)f2bf(acc[st][rt][1]) << 16);
          u.y = (unsigned)f2bf(acc[st][rt][2]) | ((unsigned)f2bf(acc[st][rt][3]) << 16);
          *(uint2*)&((unsigned short*)Out)[row * N + col] = u;
        } else {
          *(f32x4*)&((float*)Out)[row * N + col] = acc[st][rt];
        }
      }
    }

    // ---- convert prefetched regs into other buffer ----
    if (more) {
#pragma unroll
      for (int j = 0; j < 8; ++j) {
        const int row = j * 8 + wave;
        uint2 u;
        u.x = (unsigned)f2bf(pf[j].x) | ((unsigned)f2bf(pf[j].y) << 16);
        u.y = (unsigned)f2bf(pf[j].z) | ((unsigned)f2bf(pf[j].w) << 16);
        *(uint2*)&lds[p ^ 1][row * LDSTRIDE + lane * 4] = u;
      }
      __syncthreads();
    }
    p ^= 1;
    t = tn;
  }
}

// ---------------------------------------------------------------
// Fused: qp = queries@W_q + b_q  (N=384), softmax over 16 logits per
// (q,h) + sampling points. One block per 32-query tile.
// ---------------------------------------------------------------
__global__ __launch_bounds__(512, 2) void qproj_softmax_kernel(
    const float* __restrict__ A, const float* __restrict__ W,
    const float* __restrict__ bias, const float* __restrict__ refp,
    float* __restrict__ attn, float* __restrict__ pts) {
  constexpr int N = 384;
  __shared__ __align__(16) char smem[32 * 392 * 4];
  short* slds = (short*)smem;
  float* sout = (float*)smem;
  const int tid  = threadIdx.x;
  const int lane = tid & 63;
  const int wave = tid >> 6;
  const int quad = lane >> 4;
  const int ln   = lane & 15;

  s16x8 bfrag[3][8];
  float bv[3];
#pragma unroll
  for (int st = 0; st < 3; ++st) {
    const int ng = st * 128 + wave * 16 + ln;
    bv[st] = bias[ng];
#pragma unroll
    for (int ks = 0; ks < 8; ++ks) {
      s16x8 f;
#pragma unroll
      for (int j = 0; j < 8; ++j)
        f[j] = (short)f2bf(W[(ks * 32 + quad * 8 + j) * N + ng]);
      bfrag[st][ks] = f;
    }
  }

  const size_t rowBase = (size_t)blockIdx.x * 32;
  {
    // coalesced staging: f4-index i = j*512+tid, row=i>>6, col4=lane
    const float* Ab = A + rowBase * 256;
#pragma unroll
    for (int j = 0; j < 4; ++j) {
      float4 v = ((const float4*)Ab)[j * 512 + tid];
      const int row = j * 8 + wave;
      uint2 u;
      u.x = (unsigned)f2bf(v.x) | ((unsigned)f2bf(v.y) << 16);
      u.y = (unsigned)f2bf(v.z) | ((unsigned)f2bf(v.w) << 16);
      *(uint2*)&slds[row * 264 + lane * 4] = u;
    }
  }
  __syncthreads();

  f32x4 acc[3][2];
#pragma unroll
  for (int st = 0; st < 3; ++st) {
    acc[st][0] = f32x4{bv[st], bv[st], bv[st], bv[st]};
    acc[st][1] = acc[st][0];
  }
#pragma unroll
  for (int ks = 0; ks < 8; ++ks) {
    s16x8 a0 = *(const s16x8*)&slds[ln * 264 + ks * 32 + quad * 8];
    s16x8 a1 = *(const s16x8*)&slds[(ln + 16) * 264 + ks * 32 + quad * 8];
#pragma unroll
    for (int st = 0; st < 3; ++st) {
      acc[st][0] = MFMA(a0, bfrag[st][ks], acc[st][0]);
      acc[st][1] = MFMA(a1, bfrag[st][ks], acc[st][1]);
    }
  }
  __syncthreads();  // done reading slds (aliased with sout)

#pragma unroll
  for (int st = 0; st < 3; ++st) {
    const int ng = st * 128 + wave * 16 + ln;
#pragma unroll
    for (int rt = 0; rt < 2; ++rt)
#pragma unroll
      for (int r = 0; r < 4; ++r)
        sout[(rt * 16 + quad * 4 + r) * 392 + ng] = acc[st][rt][r];
  }
  __syncthreads();

  if (tid < 256) {
    const int ql = tid >> 3, h = tid & 7;
    const float* basep = sout + ql * 392 + h * 48;
    float s[16];
    float mx = -1e30f;
#pragma unroll
    for (int lp = 0; lp < 16; ++lp) {
      s[lp] = basep[lp * 3 + 2];
      mx = fmaxf(mx, s[lp]);
    }
    float sum = 0.f;
#pragma unroll
    for (int lp = 0; lp < 16; ++lp) {
      s[lp] = __expf(s[lp] - mx);
      sum += s[lp];
    }
    const float inv = 1.0f / sum;
    const size_t q   = rowBase + ql;
    const size_t gq8 = q * 8 + h;
    float* ao = attn + gq8 * 16;
#pragma unroll
    for (int lp = 0; lp < 16; ++lp) ao[lp] = s[lp] * inv;

    const float rx = refp[q * 2], ry = refp[q * 2 + 1];
    float* po = pts + gq8 * 32;
    const float invsh[4] = {1.f / 128.f, 1.f / 64.f, 1.f / 32.f, 1.f / 16.f};
#pragma unroll
    for (int l = 0; l < 4; ++l) {
#pragma unroll
      for (int p = 0; p < 4; ++p) {
        const int lp = l * 4 + p;
        po[lp * 2 + 0] = rx + basep[lp * 3 + 0] * invsh[l];
        po[lp * 2 + 1] = ry + basep[lp * 3 + 1] * invsh[l];
      }
    }
  }
}

// ---------------------------------------------------------------
// MSDA sampling v3: 256 thr / 8 queries per block.
// Phase1: 1024 (q,h,lp) items -> folded weights + bases in LDS.
// Phase2: 4 lanes per corner-row, dwordx4 gathers (16B/lane),
// 4 corner loads batched before accumulation; float2 accumulators.
// ---------------------------------------------------------------
__global__ __launch_bounds__(256) void msda_sample_kernel(
    const unsigned int* __restrict__ imgp,  // bf16 pairs, [B*I][128] uints
    const float* __restrict__ attn, const float* __restrict__ pts,
    float* __restrict__ out) {
  __shared__ __align__(16) float sw[1024][4];
  __shared__ __align__(16) int   sib[1024][4];
  const int bid = blockIdx.x;        // group of 8 queries
  const int tid = threadIdx.x;

#pragma unroll
  for (int it = 0; it < 4; ++it) {
    const int i  = it * 256 + tid;   // 0..1023
    const int q  = i >> 7;
    const int h  = (i >> 4) & 7;
    const int lp = i & 15;
    const int l  = lp >> 2;
    const int gq = bid * 8 + q;
    const int b  = gq >> 10;
    const int ww = 128 >> l;
    const int start = (l > 0 ? 16384 : 0) + (l > 1 ? 4096 : 0) + (l > 2 ? 1024 : 0);
    const float2 p = *(const float2*)&pts[((size_t)gq * 8 + h) * 32 + lp * 2];
    const float a  = attn[((size_t)gq * 8 + h) * 16 + lp];
    const float x = p.x * (float)ww - 0.5f;
    const float y = p.y * (float)ww - 0.5f;
    const float x0f = floorf(x), y0f = floorf(y);
    const float wx = x - x0f, wy = y - y0f;
    const int x0 = (int)x0f, y0 = (int)y0f;
    const float cw[4] = {(1.f - wx) * (1.f - wy), wx * (1.f - wy),
                         (1.f - wx) * wy,          wx * wy};
#pragma unroll
    for (int c = 0; c < 4; ++c) {
      const int xi = x0 + (c & 1), yi = y0 + (c >> 1);
      const bool valid = (xi >= 0) & (xi < ww) & (yi >= 0) & (yi < ww);
      const int xc = min(max(xi, 0), ww - 1);
      const int yc = min(max(yi, 0), ww - 1);
      const int idx = start + yc * ww + xc;
      sw[i][c]  = valid ? a * cw[c] : 0.f;
      sib[i][c] = ((b * I_ + idx) << 7) + (h << 4);  // uint (bf16-pair) units
    }
  }
  __syncthreads();

  const int q  = tid >> 5;        // 0..7
  const int h  = (tid >> 2) & 7;  // 0..7
  const int c8 = tid & 3;         // 0..3, channels 8*c8..8*c8+7
  float2 acc[4];
#pragma unroll
  for (int k = 0; k < 4; ++k) acc[k] = float2{0.f, 0.f};

#define BFLO(v) __uint_as_float((v) << 16)
#define BFHI(v) __uint_as_float((v) & 0xffff0000u)
#pragma unroll
  for (int lp = 0; lp < 16; ++lp) {
    const int sidx = q * 128 + h * 16 + lp;
    const float4 w4 = *(const float4*)sw[sidx];
    const int4   i4 = *(const int4*)sib[sidx];
    const uint4 u0 = *(const uint4*)&imgp[i4.x + c8 * 4];
    const uint4 u1 = *(const uint4*)&imgp[i4.y + c8 * 4];
    const uint4 u2 = *(const uint4*)&imgp[i4.z + c8 * 4];
    const uint4 u3 = *(const uint4*)&imgp[i4.w + c8 * 4];
#define ACCUM(U, WGT)                                        \
    acc[0].x += (WGT) * BFLO(U.x); acc[0].y += (WGT) * BFHI(U.x); \
    acc[1].x += (WGT) * BFLO(U.y); acc[1].y += (WGT) * BFHI(U.y); \
    acc[2].x += (WGT) * BFLO(U.z); acc[2].y += (WGT) * BFHI(U.z); \
    acc[3].x += (WGT) * BFLO(U.w); acc[3].y += (WGT) * BFHI(U.w);
    ACCUM(u0, w4.x)
    ACCUM(u1, w4.y)
    ACCUM(u2, w4.z)
    ACCUM(u3, w4.w)
#undef ACCUM
  }
#undef BFLO
#undef BFHI

  const int gq = bid * 8 + q;
  float* dst = &out[(size_t)gq * 256 + h * 32 + c8 * 8];
  float4 r0{acc[0].x, acc[0].y, acc[1].x, acc[1].y};
  float4 r1{acc[2].x, acc[2].y, acc[3].x, acc[3].y};
  *(float4*)dst = r0;
  *(float4*)(dst + 4) = r1;
}

// ---------------------------------------------------------------
// workspace layout (bytes)
// ---------------------------------------------------------------
#define OFF_IMGP 0ULL                        // 174080*256*2 = 89,128,960 (bf16)
#define OFF_ATTN 89128960ULL                 // 8192*8*16*4  =  4,194,304
#define OFF_PTS  93323264ULL                 // 8192*8*32*4  =  8,388,608
#define OFF_MSDA 101711872ULL                // 8192*256*4   =  8,388,608
#define WS_NEEDED 110100480ULL

extern "C" void kernel_launch(void* const* d_in, const int* in_sizes, int n_in,
                              void* d_out, int out_size, void* d_ws, size_t ws_size,
                              hipStream_t stream) {
  const float* img     = (const float*)d_in[0];
  const float* queries = (const float*)d_in[2];
  const float* refp    = (const float*)d_in[3];
  const float* W_img   = (const float*)d_in[4];
  const float* b_img   = (const float*)d_in[5];
  const float* W_q     = (const float*)d_in[6];
  const float* b_q     = (const float*)d_in[7];
  const float* W_out   = (const float*)d_in[8];
  const float* b_out   = (const float*)d_in[9];

  if (ws_size < WS_NEEDED) return;

  char* ws = (char*)d_ws;
  unsigned short* imgp = (unsigned short*)(ws + OFF_IMGP);
  float* attn = (float*)(ws + OFF_ATTN);
  float* pts  = (float*)(ws + OFF_PTS);
  float* msda = (float*)(ws + OFF_MSDA);

  // img_p = img @ W_img + b_img  (174080 x 256) -> bf16; 2720 M64-tiles
  hipLaunchKernelGGL((gemm64<true>), dim3(256), dim3(512), 0, stream,
                     img, W_img, b_img, (void*)imgp, I_ * B_ / 64);
  // fused qp GEMM + softmax + sampling points
  hipLaunchKernelGGL(qproj_softmax_kernel, dim3(B_ * NQ_ / 32), dim3(512), 0, stream,
                     queries, W_q, b_q, refp, attn, pts);
  // bilinear sampling + attention reduce (8 queries per block)
  hipLaunchKernelGGL(msda_sample_kernel, dim3(B_ * NQ_ / 8), dim3(256), 0, stream,
                     (const unsigned int*)imgp, attn, pts, msda);
  // out = msda @ W_out + b_out   (8192 x 256) -> fp32; 128 M64-tiles
  hipLaunchKernelGGL((gemm64<false>), dim3(128), dim3(512), 0, stream,
                     msda, W_out, b_out, d_out, 128);
}